// Round 1
// 95.819 us; speedup vs baseline: 1.0230x; 1.0230x over previous
//
#include <hip/hip_runtime.h>
#include <math.h>

#define NPERSEG 1024
#define STEP    256
#define NWIN    61
#define SEQ     16384
#define BATCH   1024

typedef float f32x4 __attribute__((ext_vector_type(4)));

// ---------------------------------------------------------------------------
// Setup kernel: compute the 6 weight tables once (they depend only on the
// element index 0..1023, never on the batch row). 4 blocks x 256 threads,
// one element per thread, 4 precise sincosf each. Arithmetic is IDENTICAL
// (same order, same ops) to the old per-block prologue, so the main kernel's
// results stay bit-exact vs the previous passing kernel.
//
// Layout in d_ws (floats):  W[table*1024 + idx], tables:
//   0=Fc (full cos)  1=Fs (full sin)  2=Pc (prefix cos)  3=Ps (prefix sin)
//   4=Sc (suffix cos) 5=Ss (suffix sin)
// Thread t of the main kernel reads element block 4t..4t+3 of each table as
// one f32x4 -> perfectly coalesced.
// ---------------------------------------------------------------------------
__global__ __launch_bounds__(256) void welch_weights_kernel(
        const float* __restrict__ freqs,
        float* __restrict__ W) {
    const int idx = blockIdx.x * 256 + threadIdx.x;   // 0..1023
    const int p0  = idx & 255;
    const int q   = idx >> 8;                          // 0..3
    float fc_ = 0.f, fs_ = 0.f, pc_ = 0.f, ps_ = 0.f, sc_ = 0.f, ss_ = 0.f;
    #pragma unroll
    for (int k = 0; k < 4; ++k) {
        float a = 6.2831853071795864769f * freqs[p0 + 256 * k];
        float sv, cv;
        sincosf(a, &sv, &cv);
        cv *= (1.0f / NWIN);
        sv *= -(1.0f / NWIN);     // reference uses -sin
        fc_ += cv; fs_ += sv;
        if (k <= q) { pc_ += cv; ps_ += sv; }
        if (k >= q) { sc_ += cv; ss_ += sv; }
    }
    W[0 * 1024 + idx] = fc_;
    W[1 * 1024 + idx] = fs_;
    W[2 * 1024 + idx] = pc_;
    W[3 * 1024 + idx] = ps_;
    W[4 * 1024 + idx] = sc_;
    W[5 * 1024 + idx] = ss_;
}

// ---------------------------------------------------------------------------
// Main kernel: pure 64 MB stream + 2 FMAs/element. Weight tables arrive as
// 6 coalesced f32x4 loads (L2-resident after the first blocks) that overlap
// with the row stream. No transcendentals, no gathers, no scratch.
// ---------------------------------------------------------------------------
__global__ __launch_bounds__(256, 4) void welch_fused_kernel(
        const float* __restrict__ inp,
        const float* __restrict__ W,
        const float* __restrict__ fc_w,
        const float* __restrict__ fc_b,
        float* __restrict__ out) {
    const int row = blockIdx.x;
    const int t   = threadIdx.x;

    const f32x4* __restrict__ W4 = (const f32x4*)W;
    // 6 x 16B coalesced table loads; issue first so they're in flight
    // alongside the row loads.
    f32x4 Fc = W4[0 * 256 + t];
    f32x4 Fs = W4[1 * 256 + t];
    f32x4 Pc = W4[2 * 256 + t];
    f32x4 Ps = W4[3 * 256 + t];
    f32x4 Sc = W4[4 * 256 + t];
    f32x4 Ss = W4[5 * 256 + t];

    const f32x4* __restrict__ x4 = (const f32x4*)(inp + (size_t)row * SEQ);

    // Preload the whole row slice (16 x 16B = 64 VGPRs). With the 6 weight
    // vectors (~24 VGPRs) + bookkeeping this sits ~110 VGPRs, inside the
    // 128-reg budget of __launch_bounds__(256, 4); the compiler hoists as
    // many loads as fit and software-pipelines the rest.
    f32x4 X[16];
    #pragma unroll
    for (int i = 0; i < 16; ++i) X[i] = x4[t + 256 * i];

    // i = 0: prefix weights
    float sr = X[0].x * Pc.x + X[0].y * Pc.y + X[0].z * Pc.z + X[0].w * Pc.w;
    float si = X[0].x * Ps.x + X[0].y * Ps.y + X[0].z * Ps.z + X[0].w * Ps.w;
    // i = 1..14: full-sum weights
    #pragma unroll
    for (int i = 1; i < 15; ++i) {
        sr += X[i].x * Fc.x + X[i].y * Fc.y + X[i].z * Fc.z + X[i].w * Fc.w;
        si += X[i].x * Fs.x + X[i].y * Fs.y + X[i].z * Fs.z + X[i].w * Fs.w;
    }
    // i = 15: suffix weights
    sr += X[15].x * Sc.x + X[15].y * Sc.y + X[15].z * Sc.z + X[15].w * Sc.w;
    si += X[15].x * Ss.x + X[15].y * Ss.y + X[15].z * Ss.z + X[15].w * Ss.w;

    // wave64 butterfly reduce
    #pragma unroll
    for (int off = 32; off > 0; off >>= 1) {
        sr += __shfl_down(sr, off, 64);
        si += __shfl_down(si, off, 64);
    }

    __shared__ float red[4][2];
    const int wave = t >> 6;
    const int lane = t & 63;
    if (lane == 0) { red[wave][0] = sr; red[wave][1] = si; }
    __syncthreads();

    if (t == 0) {
        float fr = red[0][0] + red[1][0] + red[2][0] + red[3][0];
        float fi = red[0][1] + red[1][1] + red[2][1] + red[3][1];
        out[row] = (fr * fr + fi * fi) * fc_w[0] + fc_b[0];
    }
}

extern "C" void kernel_launch(void* const* d_in, const int* in_sizes, int n_in,
                              void* d_out, int out_size, void* d_ws, size_t ws_size,
                              hipStream_t stream) {
    const float* inp   = (const float*)d_in[0];   // (1024, 16384) f32
    const float* freqs = (const float*)d_in[1];   // (1024,) f32
    const float* fc_w  = (const float*)d_in[2];   // (1,1) f32
    const float* fc_b  = (const float*)d_in[3];   // (1,) f32
    float* out = (float*)d_out;                   // (1024, 1) f32
    float* W   = (float*)d_ws;                    // 6*1024 floats = 24 KB

    // d_ws is re-poisoned by the harness each iteration -> recompute weights
    // every launch (4 blocks, ~1k sincosf total, a few microseconds).
    welch_weights_kernel<<<4, 256, 0, stream>>>(freqs, W);
    welch_fused_kernel<<<BATCH, 256, 0, stream>>>(inp, W, fc_w, fc_b, out);
}

// Round 2
// 92.786 us; speedup vs baseline: 1.0564x; 1.0327x over previous
//
#include <hip/hip_runtime.h>
#include <math.h>

#define NPERSEG 1024
#define STEP    256
#define NWIN    61
#define SEQ     16384
#define BATCH   1024

typedef float f32x4 __attribute__((ext_vector_type(4)));
typedef float f32x2 __attribute__((ext_vector_type(2)));

// Single fused kernel.
//   out[b] = (fr^2 + fi^2)*fc_w + fc_b,  fr = (1/61) sum_s x[b,s]*wc[s], etc.
// Weight structure: element idx = 4t+e (0..1023), p0 = idx&255, q = idx>>8.
//   i = 0     -> prefix weights  (k = 0..q)
//   i = 1..14 -> full weights    (k = 0..3)
//   i = 15    -> suffix weights  (k = q..3)
//
// Changes vs r1 (two-kernel version):
//  * ONE launch: the 1024 (cos,sin) pairs are computed cooperatively per
//    block (4 sincosf/thread, not 16 as in r0) and shared via 8 KB LDS.
//  * The 16 row loads are issued BEFORE the sincos prologue, so the
//    transcendental work executes entirely under HBM latency — the kernel's
//    critical path stays the pure 64 MB stream.
//  * Identical arithmetic order everywhere -> bit-exact vs r0/r1.
__global__ __launch_bounds__(256, 4) void welch_fused_kernel(
        const float* __restrict__ inp,
        const float* __restrict__ freqs,
        const float* __restrict__ fc_w,
        const float* __restrict__ fc_b,
        float* __restrict__ out) {
    const int row = blockIdx.x;
    const int t   = threadIdx.x;

    const f32x4* __restrict__ x4 = (const f32x4*)(inp + (size_t)row * SEQ);

    // Issue the whole 64 KB row slice first (16 x dwordx4 per thread).
    // These have no dependencies; the compiler keeps them in flight while
    // the VALU does the sincos prologue below.
    f32x4 X[16];
    #pragma unroll
    for (int i = 0; i < 16; ++i) X[i] = x4[t + 256 * i];

    // Cooperative weight prologue: thread t owns freqs[4t..4t+3].
    // cs[j] = ( cos(2*pi*f_j)/61 , -sin(2*pi*f_j)/61 )  -- same values, same
    // order as the r1 weights kernel -> bit-exact.
    __shared__ f32x2 cs[NPERSEG];
    {
        f32x4 f = ((const f32x4*)freqs)[t];
        #pragma unroll
        for (int e = 0; e < 4; ++e) {
            float a = 6.2831853071795864769f * f[e];
            float sv, cv;
            sincosf(a, &sv, &cv);
            f32x2 v;
            v.x = cv * (1.0f / NWIN);
            v.y = sv * (-(1.0f / NWIN));
            cs[4 * t + e] = v;
        }
    }
    __syncthreads();

    // Build the 6 per-element weight scalars in registers (clamp logic
    // identical to r0/r1: prefix k<=q, suffix k>=q).
    float Fc[4], Fs[4], Pc[4], Ps[4], Sc[4], Ss[4];
    #pragma unroll
    for (int e = 0; e < 4; ++e) {
        const int idx = 4 * t + e;
        const int p0  = idx & 255;
        const int q   = idx >> 8;
        float fc_ = 0.f, fs_ = 0.f, pc_ = 0.f, ps_ = 0.f, sc_ = 0.f, ss_ = 0.f;
        #pragma unroll
        for (int k = 0; k < 4; ++k) {
            f32x2 v = cs[p0 + 256 * k];
            fc_ += v.x; fs_ += v.y;
            if (k <= q) { pc_ += v.x; ps_ += v.y; }
            if (k >= q) { sc_ += v.x; ss_ += v.y; }
        }
        Fc[e] = fc_; Fs[e] = fs_;
        Pc[e] = pc_; Ps[e] = ps_;
        Sc[e] = sc_; Ss[e] = ss_;
    }

    // Main body: 2 FMAs per element on the preloaded row.
    float sr = X[0].x * Pc[0] + X[0].y * Pc[1] + X[0].z * Pc[2] + X[0].w * Pc[3];
    float si = X[0].x * Ps[0] + X[0].y * Ps[1] + X[0].z * Ps[2] + X[0].w * Ps[3];
    #pragma unroll
    for (int i = 1; i < 15; ++i) {
        sr += X[i].x * Fc[0] + X[i].y * Fc[1] + X[i].z * Fc[2] + X[i].w * Fc[3];
        si += X[i].x * Fs[0] + X[i].y * Fs[1] + X[i].z * Fs[2] + X[i].w * Fs[3];
    }
    sr += X[15].x * Sc[0] + X[15].y * Sc[1] + X[15].z * Sc[2] + X[15].w * Sc[3];
    si += X[15].x * Ss[0] + X[15].y * Ss[1] + X[15].z * Ss[2] + X[15].w * Ss[3];

    // wave64 butterfly reduce
    #pragma unroll
    for (int off = 32; off > 0; off >>= 1) {
        sr += __shfl_down(sr, off, 64);
        si += __shfl_down(si, off, 64);
    }

    __shared__ float red[4][2];
    const int wave = t >> 6;
    const int lane = t & 63;
    if (lane == 0) { red[wave][0] = sr; red[wave][1] = si; }
    __syncthreads();

    if (t == 0) {
        float fr = red[0][0] + red[1][0] + red[2][0] + red[3][0];
        float fi = red[0][1] + red[1][1] + red[2][1] + red[3][1];
        out[row] = (fr * fr + fi * fi) * fc_w[0] + fc_b[0];
    }
}

extern "C" void kernel_launch(void* const* d_in, const int* in_sizes, int n_in,
                              void* d_out, int out_size, void* d_ws, size_t ws_size,
                              hipStream_t stream) {
    const float* inp   = (const float*)d_in[0];   // (1024, 16384) f32
    const float* freqs = (const float*)d_in[1];   // (1024,) f32
    const float* fc_w  = (const float*)d_in[2];   // (1,1) f32
    const float* fc_b  = (const float*)d_in[3];   // (1,) f32
    float* out = (float*)d_out;                   // (1024, 1) f32

    welch_fused_kernel<<<BATCH, 256, 0, stream>>>(inp, freqs, fc_w, fc_b, out);
}